// Round 2
// baseline (382.516 us; speedup 1.0000x reference)
//
#include <hip/hip_runtime.h>
#include <math.h>

#define B 4
#define C 64
#define L 4096
#define OUTC 64
#define SCALE 10.0f
#define THRESH 1e-3f

typedef float v4f __attribute__((ext_vector_type(4)));
typedef short bf16x8 __attribute__((ext_vector_type(8)));
typedef unsigned short us8 __attribute__((ext_vector_type(8)));

__device__ __forceinline__ unsigned short f2bf(float x) {
    unsigned int u = __float_as_uint(x);
    u += 0x7fffu + ((u >> 16) & 1u);          // round-to-nearest-even
    return (unsigned short)(u >> 16);
}
__device__ __forceinline__ float bf2f(unsigned short h) {
    return __uint_as_float(((unsigned int)h) << 16);
}
__device__ __forceinline__ v4f mfma16(bf16x8 a, bf16x8 b, v4f c) {
    return __builtin_amdgcn_mfma_f32_16x16x32_bf16(a, b, c, 0, 0, 0);
}

// ---------------------------------------------------------------------------
// FRAGMENT-TILED operand layout (ushort units):
//   T(b,tile,chunk,lane,j) = ((b*256 + tile)*2 + chunk)*512 + lane*8 + j
// tile = col/16, chunk = c/32, lane = ((c&31)>>3)*16 + (col&15), j = c&7.
// Fragment load = base + lane*16B -> one contiguous 1 KB wave transaction.
//
// R1 CHANGE — SINGLE-COMPUTE SCORES (registers replace the recompute pass):
// Previous structure computed every S element TWICE (pass1 for row sums,
// pass2 recompute for normalize+threshold) because 32 rows of exp values
// don't fit anywhere. At 16 rows/block the exp values are exactly 128
// VGPRs/thread (e[32][4] f32, statically indexed, loops fully unrolled).
// Pass 2 becomes a pure register replay: no K loads, no MFMA, no exp.
// Wave->column assignment in pass 1 is STRIDED (ct16 = T*8 + wave) so that
// store-tile T's 128 columns live one 16-col subtile per wave -> the proven
// Pt-transpose cooperative store pattern is unchanged. Numerically
// bit-identical to the recompute version (same ops, just stored).
// XCD remap (batch b -> XCDs {2b,2b+1}) + NT output stores kept from R0.
// ---------------------------------------------------------------------------

// ---------------------------------------------------------------------------
// Projection: p = l2norm(W2 @ leaky(W1 @ x)) per column, emitted as bf16
// hi/lo planes directly in the fragment-tiled layout above.
// 512 blocks x 256 threads; block->(which,b,ltile) decode is XCD-pinned.
// ---------------------------------------------------------------------------
__global__ void __launch_bounds__(256) proj_kernel(
    const float* __restrict__ q_in, const float* __restrict__ k_in,
    const float* __restrict__ W1, const float* __restrict__ W2,
    unsigned short* __restrict__ Qh, unsigned short* __restrict__ Ql,
    unsigned short* __restrict__ Kh, unsigned short* __restrict__ Kl)
{
    int bid   = blockIdx.x;        // 0..511
    int xcd   = bid & 7;
    int b     = xcd >> 1;
    int which = (bid >> 3) & 1;    // 0 = query, 1 = key
    int lt    = ((bid >> 4) << 1) | (xcd & 1);   // 0..63
    int l0    = lt << 6;
    int t     = threadIdx.x;
    int g     = t >> 6;            // 0..3  (owns channels [g*16, g*16+16))
    int l     = t & 63;

    const float* __restrict__ src =
        (which ? k_in : q_in) + (size_t)b * C * L + l0 + l;
    unsigned short* __restrict__ dh = which ? Kh : Qh;
    unsigned short* __restrict__ dl = which ? Kl : Ql;

    __shared__ float Ht[128][65];   // [h][l], pad 65 -> conflict-free
    __shared__ float red[4][64];

    float xr[C];
    #pragma unroll
    for (int c = 0; c < C; ++c)
        xr[c] = src[(size_t)c * L];

    // Stage 1: H[o][l] for o in [g*32, g*32+32)
    #pragma unroll 1
    for (int oo = 0; oo < 32; oo += 4) {
        #pragma unroll
        for (int u = 0; u < 4; ++u) {
            int o = g * 32 + oo + u;
            float h0 = 0.f, h1 = 0.f, h2 = 0.f, h3 = 0.f;
            #pragma unroll
            for (int c = 0; c < C; c += 4) {
                h0 = fmaf(W1[o * C + c + 0], xr[c + 0], h0);
                h1 = fmaf(W1[o * C + c + 1], xr[c + 1], h1);
                h2 = fmaf(W1[o * C + c + 2], xr[c + 2], h2);
                h3 = fmaf(W1[o * C + c + 3], xr[c + 3], h3);
            }
            float h = (h0 + h1) + (h2 + h3);
            Ht[o][l] = (h >= 0.0f) ? h : 0.01f * h;   // LeakyReLU(0.01)
        }
    }
    __syncthreads();

    // Stage 2: Y[o][l] for o in [g*16, g*16+16)
    float y[16];
    #pragma unroll
    for (int u = 0; u < 16; ++u) y[u] = 0.f;

    #pragma unroll 1
    for (int hh = 0; hh < 2 * C; hh += 16) {
        float hr[16];
        #pragma unroll
        for (int r = 0; r < 16; ++r)
            hr[r] = Ht[hh + r][l];
        #pragma unroll
        for (int u = 0; u < 16; ++u) {
            int o = g * 16 + u;
            #pragma unroll
            for (int h = 0; h < 16; ++h)
                y[u] = fmaf(W2[o * (2 * C) + hh + h], hr[h], y[u]);
        }
    }

    // l2norm over all 64 output channels (cross-group via LDS)
    float ss = 0.f;
    #pragma unroll
    for (int u = 0; u < 16; ++u) ss = fmaf(y[u], y[u], ss);
    red[g][l] = ss;
    __syncthreads();
    float tot = red[0][l] + red[1][l] + red[2][l] + red[3][l];
    float inv = 1.0f / fmaxf(sqrtf(tot), 1e-12f);

    // Emit bf16 hi/lo split in fragment-tiled layout.
    unsigned short hs[16], ls[16];
    #pragma unroll
    for (int u = 0; u < 16; ++u) {
        float val = y[u] * inv;
        hs[u] = f2bf(val);
        ls[u] = f2bf(val - bf2f(hs[u]));
    }
    {
        int col   = l0 + l;
        int tile  = col >> 4;
        int lnn   = col & 15;
        int chunk = g >> 1;
        int quad0 = (g & 1) * 2;
        size_t base0 = (((size_t)b * 256 + tile) * 2 + chunk) * 512
                     + (size_t)(quad0 * 16 + lnn) * 8;
        size_t base1 = base0 + 128;   // quad0+1 -> lane+16 -> +128 ushorts
        *(us8*)(dh + base0) = *(us8*)&hs[0];
        *(us8*)(dh + base1) = *(us8*)&hs[8];
        *(us8*)(dl + base0) = *(us8*)&ls[0];
        *(us8*)(dl + base1) = *(us8*)&ls[8];
    }
}

// ---------------------------------------------------------------------------
// Single-compute scores kernel: MFMA bf16x3, softmax(fixed shift 10),
// threshold. 1024 blocks (XCD-pinned decode) x 512 threads (8 waves);
// 16 q-rows per block. S computed ONCE; exp values held in registers
// (e[32][4] f32 = 128 VGPRs, statically indexed) across the row-sum
// reduction; pass 2 is a register replay -> no K re-read, no 2nd MFMA.
// S = Qh*Kh + Qh*Kl + Ql*Kh (lo*lo dropped). |S|<=10 -> fixed shift 10.
// ---------------------------------------------------------------------------
__global__ void __launch_bounds__(512) scores_kernel(
    const unsigned short* __restrict__ Qh, const unsigned short* __restrict__ Ql,
    const unsigned short* __restrict__ Kh, const unsigned short* __restrict__ Kl,
    float* __restrict__ out)
{
    int bid  = blockIdx.x;          // 0..1023
    // XCD-locality decode: batch b = (bid&7)>>1 -> one batch's K planes
    // (~1 MB) resident in each pair of XCD L2s.
    int xcd  = bid & 7;
    int b    = xcd >> 1;
    int r0   = (((bid >> 3) << 1) | (xcd & 1)) << 4;   // 16 rows, 0..4080
    int t    = threadIdx.x;
    int wave = t >> 6;
    int lane = t & 63;
    int quad = lane >> 4;
    int ln   = lane & 15;

    // A fragments (fragment-tiled): aQ[c0][hi/lo], one 16-row tile
    bf16x8 aQ[2][2];
    {
        size_t rowtile = (size_t)b * 256 + (r0 >> 4);
        #pragma unroll
        for (int c0 = 0; c0 < 2; ++c0) {
            size_t base = (rowtile * 2 + c0) * 512 + (size_t)lane * 8;
            aQ[c0][0] = *(const bf16x8*)(Qh + base);
            aQ[c0][1] = *(const bf16x8*)(Ql + base);
        }
    }

    const size_t ktb = (size_t)b * 256;
    __shared__ float wsum[16][8];
    __shared__ float rinv[16];
    __shared__ float Pt[2][16][132];   // double-buffered transpose tile

    // ---------------- pass 1: compute exp(S-10) ONCE, keep in registers ---
    // STRIDED column assignment: iteration i covers tile ct16 = i*8 + wave,
    // i.e. global cols i*128 + wave*16 + [0,16). Store-tile i then has one
    // 16-col subtile per wave (cooperative store pattern preserved).
    float e[32][4];                 // 128 VGPRs, statically indexed
    v4f ps = (v4f){0.f, 0.f, 0.f, 0.f};

    #pragma unroll
    for (int i = 0; i < 32; ++i) {
        size_t base = ((ktb + i * 8 + wave) * 2) * 512 + (size_t)lane * 8;
        bf16x8 bh0 = *(const bf16x8*)(Kh + base);
        bf16x8 bl0 = *(const bf16x8*)(Kl + base);
        bf16x8 bh1 = *(const bf16x8*)(Kh + base + 512);
        bf16x8 bl1 = *(const bf16x8*)(Kl + base + 512);

        v4f acc = (v4f){0.f, 0.f, 0.f, 0.f};
        acc = mfma16(aQ[0][0], bh0, acc);
        acc = mfma16(aQ[0][1], bh0, acc);
        acc = mfma16(aQ[0][0], bl0, acc);
        acc = mfma16(aQ[1][0], bh1, acc);
        acc = mfma16(aQ[1][1], bh1, acc);
        acc = mfma16(aQ[1][0], bl1, acc);
        #pragma unroll
        for (int r = 0; r < 4; ++r) {
            float ev = __expf(fmaf(SCALE, acc[r], -SCALE));
            e[i][r] = ev;
            ps[r] += ev;
        }
    }

    // reduce over the 16 ln-lanes (cols) per row, then across waves via LDS
    #pragma unroll
    for (int r = 0; r < 4; ++r) {
        float s = ps[r];
        s += __shfl_xor(s, 1);
        s += __shfl_xor(s, 2);
        s += __shfl_xor(s, 4);
        s += __shfl_xor(s, 8);
        if (ln == 0) wsum[quad * 4 + r][wave] = s;
    }
    __syncthreads();
    if (t < 16) {
        float s = 0.f;
        #pragma unroll
        for (int w = 0; w < 8; ++w) s += wsum[t][w];
        rinv[t] = 1.0f / s;
    }
    __syncthreads();

    float rv[4];
    #pragma unroll
    for (int r = 0; r < 4; ++r)
        rv[r] = rinv[quad * 4 + r];

    // ---------------- pass 2: register replay, normalize, threshold, store
    float* __restrict__ outb = out + ((size_t)b * L + r0) * L;
    int srow = t >> 5;            // 0..15 (store row)
    int scol = (t & 31) * 4;      // 0..124 (16 B-aligned col)

    #pragma unroll
    for (int T = 0; T < 32; ++T) {
        int buf = T & 1;
        #pragma unroll
        for (int r = 0; r < 4; ++r) {
            float w = e[T][r] * rv[r];
            w = (w > THRESH) ? w : 0.f;
            // C/D layout: col = ln, row = quad*4 + r (m89/m91)
            Pt[buf][quad * 4 + r][wave * 16 + ln] = w;
        }
        __syncthreads();

        // line-complete cooperative store: 512 lanes x 16 B contiguous,
        // non-temporal so the store stream doesn't evict resident K planes.
        v4f o = *(const v4f*)&Pt[buf][srow][scol];
        __builtin_nontemporal_store(
            o, (v4f*)(outb + (size_t)srow * L + T * 128 + scol));
    }
}

// ---------------------------------------------------------------------------
extern "C" void kernel_launch(void* const* d_in, const int* in_sizes, int n_in,
                              void* d_out, int out_size, void* d_ws, size_t ws_size,
                              hipStream_t stream) {
    const float* query = (const float*)d_in[0];
    const float* key   = (const float*)d_in[1];
    const float* W1    = (const float*)d_in[2];
    const float* W2    = (const float*)d_in[3];
    float* out = (float*)d_out;

    // ws layout (ushorts): Qh | Ql | Kh | Kl, each B*L*OUTC = 1048576 elems
    unsigned short* Qh = (unsigned short*)d_ws;
    unsigned short* Ql = Qh + (size_t)B * L * OUTC;
    unsigned short* Kh = Ql + (size_t)B * L * OUTC;
    unsigned short* Kl = Kh + (size_t)B * L * OUTC;

    hipLaunchKernelGGL(proj_kernel, dim3(512), dim3(256), 0, stream,
                       query, key, W1, W2, Qh, Ql, Kh, Kl);
    hipLaunchKernelGGL(scores_kernel, dim3(1024), dim3(512), 0, stream,
                       Qh, Ql, Kh, Kl, out);
}

// Round 3
// 378.875 us; speedup vs baseline: 1.0096x; 1.0096x over previous
//
#include <hip/hip_runtime.h>
#include <math.h>

#define B 4
#define C 64
#define L 4096
#define OUTC 64
#define SCALE 10.0f
#define THRESH 1e-3f

typedef float v4f __attribute__((ext_vector_type(4)));
typedef short bf16x8 __attribute__((ext_vector_type(8)));
typedef unsigned short us8 __attribute__((ext_vector_type(8)));

__device__ __forceinline__ unsigned short f2bf(float x) {
    unsigned int u = __float_as_uint(x);
    u += 0x7fffu + ((u >> 16) & 1u);          // round-to-nearest-even
    return (unsigned short)(u >> 16);
}
__device__ __forceinline__ float bf2f(unsigned short h) {
    return __uint_as_float(((unsigned int)h) << 16);
}
__device__ __forceinline__ v4f mfma16(bf16x8 a, bf16x8 b, v4f c) {
    return __builtin_amdgcn_mfma_f32_16x16x32_bf16(a, b, c, 0, 0, 0);
}

// ---------------------------------------------------------------------------
// FRAGMENT-TILED operand layout (ushort units):
//   T(b,tile,chunk,lane,j) = ((b*256 + tile)*2 + chunk)*512 + lane*8 + j
// tile = col/16, chunk = c/32, lane = ((c&31)>>3)*16 + (col&15), j = c&7.
// Fragment load = base + lane*16B -> one contiguous 1 KB wave transaction.
//
// R2 CHANGE — HALF-REPLAY (single-compute win at R0's occupancy):
// R1 stored all 32 tiles of exp values (128 VGPRs) -> ~200 VGPR -> 1
// block/CU -> pass structure serialized per CU -> regression. R2 stores
// only tiles 0..15 (e[16][4] = 64 VGPRs); pass 2 replays those from
// registers and RECOMPUTES tiles 16..31 exactly as R0 did. With
// __launch_bounds__(512,4) (VGPR cap 128) this runs 2 blocks/CU like R0,
// while eliminating half the recompute MFMA/loads/exp. Bit-identical
// pipeline (same ops, same order) -> absmax must stay 0.0009994507.
// XCD remap (batch b -> XCDs {2b,2b+1}) + NT output stores kept from R0.
// ---------------------------------------------------------------------------

// ---------------------------------------------------------------------------
// Projection: p = l2norm(W2 @ leaky(W1 @ x)) per column, emitted as bf16
// hi/lo planes directly in the fragment-tiled layout above.
// 512 blocks x 256 threads; block->(which,b,ltile) decode is XCD-pinned.
// ---------------------------------------------------------------------------
__global__ void __launch_bounds__(256) proj_kernel(
    const float* __restrict__ q_in, const float* __restrict__ k_in,
    const float* __restrict__ W1, const float* __restrict__ W2,
    unsigned short* __restrict__ Qh, unsigned short* __restrict__ Ql,
    unsigned short* __restrict__ Kh, unsigned short* __restrict__ Kl)
{
    int bid   = blockIdx.x;        // 0..511
    int xcd   = bid & 7;
    int b     = xcd >> 1;
    int which = (bid >> 3) & 1;    // 0 = query, 1 = key
    int lt    = ((bid >> 4) << 1) | (xcd & 1);   // 0..63
    int l0    = lt << 6;
    int t     = threadIdx.x;
    int g     = t >> 6;            // 0..3  (owns channels [g*16, g*16+16))
    int l     = t & 63;

    const float* __restrict__ src =
        (which ? k_in : q_in) + (size_t)b * C * L + l0 + l;
    unsigned short* __restrict__ dh = which ? Kh : Qh;
    unsigned short* __restrict__ dl = which ? Kl : Ql;

    __shared__ float Ht[128][65];   // [h][l], pad 65 -> conflict-free
    __shared__ float red[4][64];

    float xr[C];
    #pragma unroll
    for (int c = 0; c < C; ++c)
        xr[c] = src[(size_t)c * L];

    // Stage 1: H[o][l] for o in [g*32, g*32+32)
    #pragma unroll 1
    for (int oo = 0; oo < 32; oo += 4) {
        #pragma unroll
        for (int u = 0; u < 4; ++u) {
            int o = g * 32 + oo + u;
            float h0 = 0.f, h1 = 0.f, h2 = 0.f, h3 = 0.f;
            #pragma unroll
            for (int c = 0; c < C; c += 4) {
                h0 = fmaf(W1[o * C + c + 0], xr[c + 0], h0);
                h1 = fmaf(W1[o * C + c + 1], xr[c + 1], h1);
                h2 = fmaf(W1[o * C + c + 2], xr[c + 2], h2);
                h3 = fmaf(W1[o * C + c + 3], xr[c + 3], h3);
            }
            float h = (h0 + h1) + (h2 + h3);
            Ht[o][l] = (h >= 0.0f) ? h : 0.01f * h;   // LeakyReLU(0.01)
        }
    }
    __syncthreads();

    // Stage 2: Y[o][l] for o in [g*16, g*16+16)
    float y[16];
    #pragma unroll
    for (int u = 0; u < 16; ++u) y[u] = 0.f;

    #pragma unroll 1
    for (int hh = 0; hh < 2 * C; hh += 16) {
        float hr[16];
        #pragma unroll
        for (int r = 0; r < 16; ++r)
            hr[r] = Ht[hh + r][l];
        #pragma unroll
        for (int u = 0; u < 16; ++u) {
            int o = g * 16 + u;
            #pragma unroll
            for (int h = 0; h < 16; ++h)
                y[u] = fmaf(W2[o * (2 * C) + hh + h], hr[h], y[u]);
        }
    }

    // l2norm over all 64 output channels (cross-group via LDS)
    float ss = 0.f;
    #pragma unroll
    for (int u = 0; u < 16; ++u) ss = fmaf(y[u], y[u], ss);
    red[g][l] = ss;
    __syncthreads();
    float tot = red[0][l] + red[1][l] + red[2][l] + red[3][l];
    float inv = 1.0f / fmaxf(sqrtf(tot), 1e-12f);

    // Emit bf16 hi/lo split in fragment-tiled layout.
    unsigned short hs[16], ls[16];
    #pragma unroll
    for (int u = 0; u < 16; ++u) {
        float val = y[u] * inv;
        hs[u] = f2bf(val);
        ls[u] = f2bf(val - bf2f(hs[u]));
    }
    {
        int col   = l0 + l;
        int tile  = col >> 4;
        int lnn   = col & 15;
        int chunk = g >> 1;
        int quad0 = (g & 1) * 2;
        size_t base0 = (((size_t)b * 256 + tile) * 2 + chunk) * 512
                     + (size_t)(quad0 * 16 + lnn) * 8;
        size_t base1 = base0 + 128;   // quad0+1 -> lane+16 -> +128 ushorts
        *(us8*)(dh + base0) = *(us8*)&hs[0];
        *(us8*)(dh + base1) = *(us8*)&hs[8];
        *(us8*)(dl + base0) = *(us8*)&ls[0];
        *(us8*)(dl + base1) = *(us8*)&ls[8];
    }
}

// ---------------------------------------------------------------------------
// Half-replay scores kernel: MFMA bf16x3, softmax(fixed shift 10),
// threshold. 1024 blocks (XCD-pinned decode) x 512 threads (8 waves);
// 16 q-rows per block; 2 blocks/CU (launch_bounds VGPR cap 128).
// Pass 1 computes exp(S-10) once for all 32 column-tiles, keeping tiles
// 0..15 in registers (e[16][4], statically indexed). Pass 2 replays tiles
// 0..15 from registers (no loads/MFMA) and recomputes tiles 16..31.
// S = Qh*Kh + Qh*Kl + Ql*Kh (lo*lo dropped). |S|<=10 -> fixed shift 10.
// ---------------------------------------------------------------------------
__global__ void __launch_bounds__(512, 4) scores_kernel(
    const unsigned short* __restrict__ Qh, const unsigned short* __restrict__ Ql,
    const unsigned short* __restrict__ Kh, const unsigned short* __restrict__ Kl,
    float* __restrict__ out)
{
    int bid  = blockIdx.x;          // 0..1023
    // XCD-locality decode: batch b = (bid&7)>>1 -> one batch's K planes
    // (~1 MB) resident in each pair of XCD L2s.
    int xcd  = bid & 7;
    int b    = xcd >> 1;
    int r0   = (((bid >> 3) << 1) | (xcd & 1)) << 4;   // 16 rows, 0..4080
    int t    = threadIdx.x;
    int wave = t >> 6;
    int lane = t & 63;
    int quad = lane >> 4;
    int ln   = lane & 15;

    // A fragments (fragment-tiled): aQ[c0][hi/lo], one 16-row tile
    bf16x8 aQ[2][2];
    {
        size_t rowtile = (size_t)b * 256 + (r0 >> 4);
        #pragma unroll
        for (int c0 = 0; c0 < 2; ++c0) {
            size_t base = (rowtile * 2 + c0) * 512 + (size_t)lane * 8;
            aQ[c0][0] = *(const bf16x8*)(Qh + base);
            aQ[c0][1] = *(const bf16x8*)(Ql + base);
        }
    }

    const size_t ktb = (size_t)b * 256;
    __shared__ float wsum[16][8];
    __shared__ float rinv[16];
    __shared__ float Pt[2][16][132];   // double-buffered transpose tile

    // ---------------- pass 1: compute exp(S-10) once ----------------------
    // STRIDED column assignment: iteration i covers tile ct16 = i*8 + wave,
    // i.e. global cols i*128 + wave*16 + [0,16). Store-tile i then has one
    // 16-col subtile per wave (cooperative store pattern preserved).
    // Tiles 0..15 keep their exp values in registers (replayed in pass 2);
    // tiles 16..31 are summed here and recomputed in pass 2 (exactly R0's
    // recompute, so the pipeline stays bit-identical).
    float e[16][4];                 // 64 VGPRs, statically indexed
    v4f ps = (v4f){0.f, 0.f, 0.f, 0.f};

    #pragma unroll
    for (int i = 0; i < 16; ++i) {
        size_t base = ((ktb + i * 8 + wave) * 2) * 512 + (size_t)lane * 8;
        bf16x8 bh0 = *(const bf16x8*)(Kh + base);
        bf16x8 bl0 = *(const bf16x8*)(Kl + base);
        bf16x8 bh1 = *(const bf16x8*)(Kh + base + 512);
        bf16x8 bl1 = *(const bf16x8*)(Kl + base + 512);

        v4f acc = (v4f){0.f, 0.f, 0.f, 0.f};
        acc = mfma16(aQ[0][0], bh0, acc);
        acc = mfma16(aQ[0][1], bh0, acc);
        acc = mfma16(aQ[0][0], bl0, acc);
        acc = mfma16(aQ[1][0], bh1, acc);
        acc = mfma16(aQ[1][1], bh1, acc);
        acc = mfma16(aQ[1][0], bl1, acc);
        #pragma unroll
        for (int r = 0; r < 4; ++r) {
            float ev = __expf(fmaf(SCALE, acc[r], -SCALE));
            e[i][r] = ev;
            ps[r] += ev;
        }
    }

    #pragma unroll 4
    for (int i = 16; i < 32; ++i) {
        size_t base = ((ktb + i * 8 + wave) * 2) * 512 + (size_t)lane * 8;
        bf16x8 bh0 = *(const bf16x8*)(Kh + base);
        bf16x8 bl0 = *(const bf16x8*)(Kl + base);
        bf16x8 bh1 = *(const bf16x8*)(Kh + base + 512);
        bf16x8 bl1 = *(const bf16x8*)(Kl + base + 512);

        v4f acc = (v4f){0.f, 0.f, 0.f, 0.f};
        acc = mfma16(aQ[0][0], bh0, acc);
        acc = mfma16(aQ[0][1], bh0, acc);
        acc = mfma16(aQ[0][0], bl0, acc);
        acc = mfma16(aQ[1][0], bh1, acc);
        acc = mfma16(aQ[1][1], bh1, acc);
        acc = mfma16(aQ[1][0], bl1, acc);
        #pragma unroll
        for (int r = 0; r < 4; ++r)
            ps[r] += __expf(fmaf(SCALE, acc[r], -SCALE));
    }

    // reduce over the 16 ln-lanes (cols) per row, then across waves via LDS
    #pragma unroll
    for (int r = 0; r < 4; ++r) {
        float s = ps[r];
        s += __shfl_xor(s, 1);
        s += __shfl_xor(s, 2);
        s += __shfl_xor(s, 4);
        s += __shfl_xor(s, 8);
        if (ln == 0) wsum[quad * 4 + r][wave] = s;
    }
    __syncthreads();
    if (t < 16) {
        float s = 0.f;
        #pragma unroll
        for (int w = 0; w < 8; ++w) s += wsum[t][w];
        rinv[t] = 1.0f / s;
    }
    __syncthreads();

    float rv[4];
    #pragma unroll
    for (int r = 0; r < 4; ++r)
        rv[r] = rinv[quad * 4 + r];

    // ---------------- pass 2a: register replay for tiles 0..15 ------------
    float* __restrict__ outb = out + ((size_t)b * L + r0) * L;
    int srow = t >> 5;            // 0..15 (store row)
    int scol = (t & 31) * 4;      // 0..124 (16 B-aligned col)

    #pragma unroll
    for (int T = 0; T < 16; ++T) {
        int buf = T & 1;
        #pragma unroll
        for (int r = 0; r < 4; ++r) {
            float w = e[T][r] * rv[r];
            w = (w > THRESH) ? w : 0.f;
            // C/D layout: col = ln, row = quad*4 + r (m89/m91)
            Pt[buf][quad * 4 + r][wave * 16 + ln] = w;
        }
        __syncthreads();

        // line-complete cooperative store: 512 lanes x 16 B contiguous,
        // non-temporal so the store stream doesn't evict resident K planes.
        v4f o = *(const v4f*)&Pt[buf][srow][scol];
        __builtin_nontemporal_store(
            o, (v4f*)(outb + (size_t)srow * L + T * 128 + scol));
    }

    // ---------------- pass 2b: recompute tiles 16..31 ---------------------
    #pragma unroll 2
    for (int T = 16; T < 32; ++T) {
        int buf = T & 1;
        size_t base = ((ktb + T * 8 + wave) * 2) * 512 + (size_t)lane * 8;
        bf16x8 bh0 = *(const bf16x8*)(Kh + base);
        bf16x8 bl0 = *(const bf16x8*)(Kl + base);
        bf16x8 bh1 = *(const bf16x8*)(Kh + base + 512);
        bf16x8 bl1 = *(const bf16x8*)(Kl + base + 512);

        v4f acc = (v4f){0.f, 0.f, 0.f, 0.f};
        acc = mfma16(aQ[0][0], bh0, acc);
        acc = mfma16(aQ[0][1], bh0, acc);
        acc = mfma16(aQ[0][0], bl0, acc);
        acc = mfma16(aQ[1][0], bh1, acc);
        acc = mfma16(aQ[1][1], bh1, acc);
        acc = mfma16(aQ[1][0], bl1, acc);
        #pragma unroll
        for (int r = 0; r < 4; ++r) {
            float w = __expf(fmaf(SCALE, acc[r], -SCALE)) * rv[r];
            w = (w > THRESH) ? w : 0.f;
            Pt[buf][quad * 4 + r][wave * 16 + ln] = w;
        }
        __syncthreads();

        v4f o = *(const v4f*)&Pt[buf][srow][scol];
        __builtin_nontemporal_store(
            o, (v4f*)(outb + (size_t)srow * L + T * 128 + scol));
    }
}

// ---------------------------------------------------------------------------
extern "C" void kernel_launch(void* const* d_in, const int* in_sizes, int n_in,
                              void* d_out, int out_size, void* d_ws, size_t ws_size,
                              hipStream_t stream) {
    const float* query = (const float*)d_in[0];
    const float* key   = (const float*)d_in[1];
    const float* W1    = (const float*)d_in[2];
    const float* W2    = (const float*)d_in[3];
    float* out = (float*)d_out;

    // ws layout (ushorts): Qh | Ql | Kh | Kl, each B*L*OUTC = 1048576 elems
    unsigned short* Qh = (unsigned short*)d_ws;
    unsigned short* Ql = Qh + (size_t)B * L * OUTC;
    unsigned short* Kh = Ql + (size_t)B * L * OUTC;
    unsigned short* Kl = Kh + (size_t)B * L * OUTC;

    hipLaunchKernelGGL(proj_kernel, dim3(512), dim3(256), 0, stream,
                       query, key, W1, W2, Qh, Ql, Kh, Kl);
    hipLaunchKernelGGL(scores_kernel, dim3(1024), dim3(512), 0, stream,
                       Qh, Ql, Kh, Kl, out);
}